// Round 21
// baseline (1041.355 us; speedup 1.0000x reference)
//
#include <hip/hip_runtime.h>

#define DECAYF 0.8f
#define OMDF   0.2f
#define EPSF   1e-5f
#define COMMITF 1.0f
#define MARGINF 0.024f
#define FIXCAP  8192
#define MAXR    64

typedef _Float16 h8v __attribute__((ext_vector_type(8)));
typedef float f4v __attribute__((ext_vector_type(4)));

__device__ inline void gload_lds16(const void* g, void* l) {
  __builtin_amdgcn_global_load_lds(
      (const __attribute__((address_space(1))) unsigned int*)g,
      (__attribute__((address_space(3))) unsigned int*)l, 16, 0, 0);
}

// ---------------- fused: zero accumulators + embed->fp16 conv + 0.5||e||^2 ----------------
// Tile tt (64 codes): 32KB at Ews + tt*32768.
// value(c,d) at byte c*512 + ((d*2) ^ swz4(c)), swz4(c) = ((c&7)<<4)|(((c>>3)&1)<<7).
__global__ __launch_bounds__(256) void k_pre(
    const float* __restrict__ embed, char* __restrict__ Ews,
    float* __restrict__ zero_p, int zero_n, float* __restrict__ ee, int K, int D)
{
  const int tid = threadIdx.x;
  const int gid0 = blockIdx.x * 256 + tid;
  const int gstride = gridDim.x * 256;

  for (int i = gid0; i < zero_n; i += gstride) zero_p[i] = 0.0f;

  for (int gid = gid0; gid < K * (D / 8); gid += gstride) {
    int k = gid >> 5;
    int d0 = (gid & 31) * 8;
    const float* ep = embed + (size_t)k * D + d0;
    float4 v0 = *(const float4*)(ep);
    float4 v1 = *(const float4*)(ep + 4);
    float f[8] = {v0.x, v0.y, v0.z, v0.w, v1.x, v1.y, v1.z, v1.w};
    h8v h;
    float ss = 0.f;
#pragma unroll
    for (int e = 0; e < 8; ++e) {
      h[e] = (_Float16)f[e];
      ss = fmaf(f[e], f[e], ss);
    }
    int tt = k >> 6;
    int c = k & 63;
    int swz4 = ((c & 7) << 4) | (((c >> 3) & 1) << 7);
    int byteoff = c * 512 + ((d0 * 2) ^ swz4);
    *(h8v*)(Ews + (size_t)tt * 32768 + byteoff) = h;
#pragma unroll
    for (int off = 1; off < 32; off <<= 1) ss += __shfl_xor(ss, off);
    if ((gid & 31) == 0) ee[k] = 0.5f * ss;
  }
}

// top-2 update with first-index tie-break (strict >)
__device__ __forceinline__ void upd2(float s, int code, float& b1, float& b2, int& bi) {
  if (s > b1) { b2 = b1; b1 = s; bi = code; }
  else if (s > b2) { b2 = s; }
}

// One tile body (barrier at end): MFMA tile TT into CUR; interleave top-2 of
// tile TT-1 (PRV). fp16 1-pass; 2-deep B-fragment register pipeline.
__device__ __forceinline__ void k_body(
    int TT, int NT, char* lds, const char* Ews, const float* ee,
    int w, int lane, int ch, int l15, int rowbyte0,
    const int (&dbyte)[8],
    const h8v (&xh)[2][8],
    f4v (&CUR)[2][2], f4v (&PRV)[2][2],
    float EEP0, float EEP1, float& EEC0, float& EEC1,
    float (&best)[2][4], float (&bst2)[2][4], int (&bidx)[2][4])
{
  const int k0 = TT * 64;
  const char* cb = lds + (TT & 1) * 32768;
  if (TT + 1 < NT) {
    const char* src = Ews + (size_t)(TT + 1) * 32768 + w * 8192 + lane * 16;
    char* dst = lds + ((TT + 1) & 1) * 32768 + w * 8192;
#pragma unroll
    for (int q = 0; q < 8; ++q) gload_lds16(src + q * 1024, dst + q * 1024);
  }
  EEC0 = ee[k0 + ch * 32 + l15];
  EEC1 = ee[k0 + ch * 32 + l15 + 16];
  const int c0p = k0 - 64 + ch * 32 + l15;
  const int c1p = c0p + 16;
#pragma unroll
  for (int rf = 0; rf < 2; ++rf) {
    CUR[rf][0] = (f4v){0.f, 0.f, 0.f, 0.f};
    CUR[rf][1] = (f4v){0.f, 0.f, 0.f, 0.f};
  }
  h8v Bh0[2], Bh1[2];
  {
    const char* p = cb + rowbyte0 + dbyte[0];
    Bh0[0] = *(const h8v*)(p);
    Bh1[0] = *(const h8v*)(p + 8192);
  }
#pragma unroll
  for (int ks = 0; ks < 8; ++ks) {
    const int cs = ks & 1, ns = cs ^ 1;
    if (ks < 7) {
      const char* p = cb + rowbyte0 + dbyte[ks + 1];
      Bh0[ns] = *(const h8v*)(p);
      Bh1[ns] = *(const h8v*)(p + 8192);
    }
    __builtin_amdgcn_s_setprio(1);
    CUR[0][0] = __builtin_amdgcn_mfma_f32_16x16x32_f16(xh[0][ks], Bh0[cs], CUR[0][0], 0, 0, 0);
    CUR[0][1] = __builtin_amdgcn_mfma_f32_16x16x32_f16(xh[0][ks], Bh1[cs], CUR[0][1], 0, 0, 0);
    CUR[1][0] = __builtin_amdgcn_mfma_f32_16x16x32_f16(xh[1][ks], Bh0[cs], CUR[1][0], 0, 0, 0);
    CUR[1][1] = __builtin_amdgcn_mfma_f32_16x16x32_f16(xh[1][ks], Bh1[cs], CUR[1][1], 0, 0, 0);
    __builtin_amdgcn_s_setprio(0);
    {
      const int rf = ks >> 2, ii = ks & 3;
      upd2(PRV[rf][0][ii] - EEP0, c0p, best[rf][ii], bst2[rf][ii], bidx[rf][ii]);
      upd2(PRV[rf][1][ii] - EEP1, c1p, best[rf][ii], bst2[rf][ii], bidx[rf][ii]);
    }
  }
  __syncthreads();
}

// ---------------- fused MFMA dist + argmax (+ near-tie flagging + CSR stats) ----------------
__global__ __launch_bounds__(256, 2) void k_dist(
    const float* __restrict__ x, const char* __restrict__ Ews,
    const float* __restrict__ ee, float* __restrict__ ind_f,
    int* __restrict__ idx_out, int* __restrict__ wl, int* __restrict__ cnt,
    int* __restrict__ cntr, int* __restrict__ rlist,
    int* __restrict__ olist, int* __restrict__ ocnt,
    int T, int K)
{
  extern __shared__ char lds[];   // 2 x 32768
  const int tid = threadIdx.x;
  const int w = tid >> 6, lane = tid & 63;
  const int l15 = lane & 15, lk = lane >> 4;
  const int rgrp = w >> 1, ch = w & 1;
  const int row0 = blockIdx.x * 64 + rgrp * 32;
  const int NT = K / 64;          // 128 (even)

  // X fragments (fp16): 2 rowfrags x 8 ksteps
  h8v xh[2][8];
#pragma unroll
  for (int rf = 0; rf < 2; ++rf) {
    const float* xp = x + (size_t)(row0 + rf * 16 + l15) * 256 + lk * 8;
#pragma unroll
    for (int ks = 0; ks < 8; ++ks) {
      float4 v0 = *(const float4*)(xp + ks * 32);
      float4 v1 = *(const float4*)(xp + ks * 32 + 4);
      float f[8] = {v0.x, v0.y, v0.z, v0.w, v1.x, v1.y, v1.z, v1.w};
      h8v h;
#pragma unroll
      for (int e = 0; e < 8; ++e) h[e] = (_Float16)f[e];
      xh[rf][ks] = h;
    }
  }

  float best[2][4], bst2[2][4];
  int bidx[2][4];
#pragma unroll
  for (int rf = 0; rf < 2; ++rf)
#pragma unroll
    for (int i = 0; i < 4; ++i) { best[rf][i] = -3.0e38f; bst2[rf][i] = -3.0e38f; bidx[rf][i] = 0; }

  const int swz = ((l15 & 7) << 4) | ((l15 >> 3) << 7);   // 4-bit swizzle: 16 distinct slots
  const int rowbyte0 = (ch * 32 + l15) * 512;
  int dbyte[8];
#pragma unroll
  for (int ks = 0; ks < 8; ++ks) dbyte[ks] = (ks * 64 + lk * 16) ^ swz;

  // prologue: stage tile 0 (32KB; 8KB per wave)
  {
    const char* src = Ews + (size_t)w * 8192 + lane * 16;
    char* dst = lds + w * 8192;
#pragma unroll
    for (int q = 0; q < 8; ++q)
      gload_lds16(src + q * 1024, dst + q * 1024);
  }
  __syncthreads();

  f4v accA[2][2], accB[2][2];
#pragma unroll
  for (int rf = 0; rf < 2; ++rf) {
    accB[rf][0] = (f4v){-3.0e38f, -3.0e38f, -3.0e38f, -3.0e38f};
    accB[rf][1] = (f4v){-3.0e38f, -3.0e38f, -3.0e38f, -3.0e38f};
  }
  float eeX0 = 0.f, eeX1 = 0.f, eeY0 = 0.f, eeY1 = 0.f;

  for (int tt = 0; tt < NT; tt += 2) {
    k_body(tt,     NT, lds, Ews, ee, w, lane, ch, l15, rowbyte0, dbyte, xh,
           accA, accB, eeX0, eeX1, eeY0, eeY1, best, bst2, bidx);
    k_body(tt + 1, NT, lds, Ews, ee, w, lane, ch, l15, rowbyte0, dbyte, xh,
           accB, accA, eeY0, eeY1, eeX0, eeX1, best, bst2, bidx);
  }
  // epilogue: top-2 of last tile (NT-1), acc in accB, ee pair in eeX
  {
    const int c0 = (NT - 1) * 64 + ch * 32 + l15, c1 = c0 + 16;
#pragma unroll
    for (int rf = 0; rf < 2; ++rf)
#pragma unroll
      for (int ii = 0; ii < 4; ++ii) {
        upd2(accB[rf][0][ii] - eeX0, c0, best[rf][ii], bst2[rf][ii], bidx[rf][ii]);
        upd2(accB[rf][1][ii] - eeX1, c1, best[rf][ii], bst2[rf][ii], bidx[rf][ii]);
      }
  }

  // reduce top-2 across the 16 column-lanes of each lk-group
#pragma unroll
  for (int rf = 0; rf < 2; ++rf)
#pragma unroll
    for (int i = 0; i < 4; ++i) {
      float s = best[rf][i], s2 = bst2[rf][i];
      int mi = bidx[rf][i];
#pragma unroll
      for (int off = 1; off < 16; off <<= 1) {
        float os = __shfl_xor(s, off);
        float os2 = __shfl_xor(s2, off);
        int oi = __shfl_xor(mi, off);
        if (os > s || (os == s && oi < mi)) {
          s2 = fmaxf(s, os2);
          s = os; mi = oi;
        } else {
          s2 = fmaxf(s2, os);
        }
      }
      best[rf][i] = s; bst2[rf][i] = s2; bidx[rf][i] = mi;
    }

  // ---- cross-ch merge via LDS (tile buffers dead after final barrier) ----
  float* S  = (float*)lds;
  float* S2 = S + 128;
  int*   MI = (int*)(S2 + 128);
  if (l15 == 0) {
#pragma unroll
    for (int rf = 0; rf < 2; ++rf)
#pragma unroll
      for (int i = 0; i < 4; ++i) {
        int rl = rf * 16 + lk * 4 + i;
        int a = rgrp * 64 + ch * 32 + rl;
        S[a]  = best[rf][i];
        S2[a] = bst2[rf][i];
        MI[a] = bidx[rf][i];
      }
  }
  __syncthreads();
  if (ch == 0 && lane < 32) {
    int a0 = rgrp * 64 + lane;
    float sA = S[a0],      s2A = S2[a0];      int miA = MI[a0];
    float sB = S[a0 + 32], s2B = S2[a0 + 32]; int miB = MI[a0 + 32];
    float s, s2; int mi;
    if (sB > sA || (sB == sA && miB < miA)) { s = sB; mi = miB; s2 = fmaxf(sA, s2B); }
    else                                    { s = sA; mi = miA; s2 = fmaxf(s2A, sB); }
    int row = row0 + lane;
    idx_out[row] = mi;
    ind_f[row] = (float)mi;
    int flagged = 0;
    if (s - s2 < MARGINF) {
      int slot = atomicAdd(cnt, 1);
      if (slot < FIXCAP) { wl[slot] = row; flagged = 1; }
    }
    if (!flagged) {
      int slot2 = atomicAdd(&cntr[mi], 1);
      if (slot2 < MAXR) rlist[mi * MAXR + slot2] = row;
      else { int o = atomicAdd(ocnt, 1); olist[o] = row; }
    }
  }
}

// ---------------- exact fp32 rescore, slice-parallel ----------------
__global__ __launch_bounds__(256) void k_fix1(
    const float* __restrict__ x, const float* __restrict__ embed,
    const float* __restrict__ ee, const int* __restrict__ wl,
    const int* __restrict__ cnt, float* __restrict__ pval,
    int* __restrict__ pidx)
{
  __shared__ float Xs[8][256];
  const int b = blockIdx.x & 255;
  const int g = blockIdx.x >> 8;
  const int t = threadIdx.x;
  int n = *cnt; if (n > FIXCAP) n = FIXCAP;
  const int c = b * 32 + (t & 31);
  const float* er = embed + (size_t)c * 256;
  const float eec = ee[c];
  const int rl = t >> 5;

  for (int r0 = g * 8; r0 < n; r0 += 32) {
    __syncthreads();
    for (int i = t; i < 8 * 64; i += 256) {
      int rr = i >> 6, dq = i & 63;
      int wi = r0 + rr; if (wi >= n) wi = n - 1;
      int row = wl[wi];
      ((float4*)Xs[rr])[dq] = *(const float4*)(x + (size_t)row * 256 + dq * 4);
    }
    __syncthreads();
    const float* xr = Xs[rl];
    float s0 = 0.f, s1 = 0.f, s2a = 0.f, s3 = 0.f;
#pragma unroll
    for (int d = 0; d < 256; d += 16) {
      float4 e0 = *(const float4*)(er + d);
      float4 e1 = *(const float4*)(er + d + 4);
      float4 e2 = *(const float4*)(er + d + 8);
      float4 e3 = *(const float4*)(er + d + 12);
      s0 = fmaf(xr[d + 0], e0.x, s0);  s0 = fmaf(xr[d + 1], e0.y, s0);
      s0 = fmaf(xr[d + 2], e0.z, s0);  s0 = fmaf(xr[d + 3], e0.w, s0);
      s1 = fmaf(xr[d + 4], e1.x, s1);  s1 = fmaf(xr[d + 5], e1.y, s1);
      s1 = fmaf(xr[d + 6], e1.z, s1);  s1 = fmaf(xr[d + 7], e1.w, s1);
      s2a = fmaf(xr[d + 8], e2.x, s2a);  s2a = fmaf(xr[d + 9], e2.y, s2a);
      s2a = fmaf(xr[d + 10], e2.z, s2a); s2a = fmaf(xr[d + 11], e2.w, s2a);
      s3 = fmaf(xr[d + 12], e3.x, s3);  s3 = fmaf(xr[d + 13], e3.y, s3);
      s3 = fmaf(xr[d + 14], e3.z, s3);  s3 = fmaf(xr[d + 15], e3.w, s3);
    }
    float s = ((s0 + s1) + (s2a + s3)) - eec;
    int mi = c;
#pragma unroll
    for (int off = 1; off < 32; off <<= 1) {
      float os = __shfl_xor(s, off);
      int oi = __shfl_xor(mi, off);
      if (os > s || (os == s && oi < mi)) { s = os; mi = oi; }
    }
    int wi = r0 + rl;
    if ((t & 31) == 0 && wi < n) {
      pval[(size_t)wi * 256 + b] = s;
      pidx[(size_t)wi * 256 + b] = mi;
    }
  }
}

// k_fix2: per flagged row, reduce 256 slice partials, write final idx + CSR stats.
__global__ __launch_bounds__(256) void k_fix2(
    const int* __restrict__ wl, const int* __restrict__ cnt,
    const float* __restrict__ pval, const int* __restrict__ pidx,
    float* __restrict__ ind_f, int* __restrict__ idx_out,
    int* __restrict__ cntr, int* __restrict__ rlist,
    int* __restrict__ olist, int* __restrict__ ocnt)
{
  __shared__ float bv[256];
  __shared__ int bi[256];
  const int t = threadIdx.x;
  int n = *cnt; if (n > FIXCAP) n = FIXCAP;
  for (int it = blockIdx.x; it < n; it += gridDim.x) {
    __syncthreads();
    bv[t] = pval[(size_t)it * 256 + t];
    bi[t] = pidx[(size_t)it * 256 + t];
    __syncthreads();
    for (int sh = 128; sh > 0; sh >>= 1) {
      if (t < sh) {
        if (bv[t + sh] > bv[t] || (bv[t + sh] == bv[t] && bi[t + sh] < bi[t])) {
          bv[t] = bv[t + sh]; bi[t] = bi[t + sh];
        }
      }
      __syncthreads();
    }
    if (t == 0) {
      int row = wl[it];
      int kf = bi[0];
      idx_out[row] = kf;
      ind_f[row] = (float)kf;
      int slot = atomicAdd(&cntr[kf], 1);
      if (slot < MAXR) rlist[kf * MAXR + slot] = row;
      else { int o = atomicAdd(ocnt, 1); olist[o] = row; }
    }
  }
}

// ---------------- k_mid: ncs+total + overflow quant/loss (olist rows; normally none) ----
__global__ __launch_bounds__(256) void k_mid(
    const float* __restrict__ cs, const int* __restrict__ cntr,
    float* __restrict__ ncs, float* __restrict__ total_acc,
    const float* __restrict__ x, const float* __restrict__ embed,
    const int* __restrict__ idx, const int* __restrict__ olist,
    const int* __restrict__ ocnt,
    float* __restrict__ quant, float* __restrict__ lslots, int K)
{
  const int tid = threadIdx.x;
  const int wave = tid >> 6, lane = tid & 63;
  int k = blockIdx.x * 256 + tid;
  float v = cs[k] * DECAYF + OMDF * (float)cntr[k];
  ncs[k] = v;
  for (int off = 32; off > 0; off >>= 1) v += __shfl_down(v, off);
  __shared__ float s4[4];
  if ((tid & 63) == 0) s4[tid >> 6] = v;
  __syncthreads();
  if (tid == 0) atomicAdd(total_acc, s4[0] + s4[1] + s4[2] + s4[3]);
  // overflow rows (normally none): quant + loss (segment sum handled by k_ema2 olist scan)
  int n = *ocnt;
  for (int i = blockIdx.x * 4 + wave; i < n; i += 128) {
    int row = olist[i];
    int kk = idx[row];
    int d0 = lane * 4;
    float4 xv = *(const float4*)(x + (size_t)row * 256 + d0);
    float4 ev = *(const float4*)(embed + (size_t)kk * 256 + d0);
    *(float4*)(quant + (size_t)row * 256 + d0) = ev;
    float dx = ev.x - xv.x, dy = ev.y - xv.y, dz = ev.z - xv.z, dw = ev.w - xv.w;
    float l = dx * dx + dy * dy + dz * dz + dw * dw;
    for (int off = 32; off > 0; off >>= 1) l += __shfl_down(l, off);
    if (lane == 0) atomicAdd(&lslots[row & 255], l);
  }
}

// ---------------- code-major segment-sum + EMA + smoothing + quant + loss ----------------
// One wave per code; embed row read ONCE per code serves all its rows' quant writes.
// Overflow (cntr>MAXR, essentially never): scan olist filtered by idx==k.
__global__ __launch_bounds__(256) void k_ema2(
    const float* __restrict__ x, const float* __restrict__ ea,
    const float* __restrict__ embed,
    const int* __restrict__ cntr, const int* __restrict__ rlist,
    const int* __restrict__ olist, const int* __restrict__ ocnt,
    const int* __restrict__ idx, const float* __restrict__ ncs,
    const float* __restrict__ total_acc, float* __restrict__ ne,
    float* __restrict__ nea, float* __restrict__ quant,
    float* __restrict__ lslots, int K, int D)
{
  int wave = threadIdx.x >> 6, lane = threadIdx.x & 63;
  int k = blockIdx.x * 4 + wave;
  if (k >= K) return;
  int c = cntr[k];
  int m = c < MAXR ? c : MAXR;
  int d0 = lane * 4;
  float4 ev = *(const float4*)(embed + (size_t)k * 256 + d0);
  float4 s = (float4){0.f, 0.f, 0.f, 0.f};
  float lsum = 0.f;
  for (int i = 0; i < m; ++i) {
    int r = rlist[k * MAXR + i];
    float4 xv = *(const float4*)(x + (size_t)r * 256 + d0);
    s.x += xv.x; s.y += xv.y; s.z += xv.z; s.w += xv.w;
    *(float4*)(quant + (size_t)r * 256 + d0) = ev;
    float dx = ev.x - xv.x, dy = ev.y - xv.y, dz = ev.z - xv.z, dw = ev.w - xv.w;
    lsum += dx * dx + dy * dy + dz * dz + dw * dw;
  }
  if (c > MAXR) {
    // rare path: remaining rows of this code live in olist (quant/loss done in k_mid)
    int n = *ocnt;
    for (int i = 0; i < n; ++i) {
      int r = olist[i];
      if (idx[r] == k) {
        float4 xv = *(const float4*)(x + (size_t)r * 256 + d0);
        s.x += xv.x; s.y += xv.y; s.z += xv.z; s.w += xv.w;
      }
    }
  }
  float4 eav = *(const float4*)(ea + (size_t)k * 256 + d0);
  float total = *total_acc;
  float csk = ncs[k];
  float sm = (csk + EPSF) / (total + (float)K * EPSF) * total;
  float rs = 1.0f / sm;
  float v0 = eav.x * DECAYF + OMDF * s.x;
  float v1 = eav.y * DECAYF + OMDF * s.y;
  float v2 = eav.z * DECAYF + OMDF * s.z;
  float v3 = eav.w * DECAYF + OMDF * s.w;
  size_t o = (size_t)k * 256 + d0;
  nea[o + 0] = v0; nea[o + 1] = v1; nea[o + 2] = v2; nea[o + 3] = v3;  // odd base: scalar stores
  ne[o + 0] = v0 * rs; ne[o + 1] = v1 * rs; ne[o + 2] = v2 * rs; ne[o + 3] = v3 * rs;
  for (int off = 32; off > 0; off >>= 1) lsum += __shfl_down(lsum, off);
  if (lane == 0 && m > 0) atomicAdd(&lslots[k & 255], lsum);
}

// ---------------- finalize commit loss ----------------
__global__ void k_loss(const float* __restrict__ lslots, float* __restrict__ out_loss,
                       float scale)
{
  int tid = threadIdx.x;
  float v = lslots[tid];
  for (int off = 32; off > 0; off >>= 1) v += __shfl_down(v, off);
  __shared__ float s4[4];
  if ((tid & 63) == 0) s4[tid >> 6] = v;
  __syncthreads();
  if (tid == 0) out_loss[0] = (s4[0] + s4[1] + s4[2] + s4[3]) * scale;
}

extern "C" void kernel_launch(void* const* d_in, const int* in_sizes, int n_in,
                              void* d_out, int out_size, void* d_ws, size_t ws_size,
                              hipStream_t stream)
{
  const float* x     = (const float*)d_in[0];
  const float* embed = (const float*)d_in[1];
  const float* cs    = (const float*)d_in[2];
  const float* ea    = (const float*)d_in[3];
  const int K = in_sizes[2];            // 8192
  const int D = in_sizes[1] / K;        // 256
  const int T = in_sizes[0] / D;        // 32768

  float* out   = (float*)d_out;
  float* o_q   = out;                        // T*D
  float* o_ind = out + (size_t)T * D;        // T
  float* o_ls  = o_ind + T;                  // 1
  float* o_ne  = o_ls + 1;                   // K*D
  float* o_ncs = o_ne + (size_t)K * D;       // K
  float* o_nea = o_ncs + K;                  // K*D

  float* w      = (float*)d_ws;
  float* ee     = w;                                    // K
  int*   idx    = (int*)(w + K);                        // T
  int*   wl     = idx + T;                              // FIXCAP
  float* pval   = (float*)(wl + FIXCAP);                // FIXCAP*256
  int*   pidx   = (int*)(pval + (size_t)FIXCAP * 256);  // FIXCAP*256
  int*   rlist  = pidx + (size_t)FIXCAP * 256;          // K*MAXR
  int*   olist  = rlist + (size_t)K * MAXR;             // T
  float* lslots = (float*)(olist + T);                  // 256  } zeroed region
  float* total  = lslots + 256;                         // 1    }
  int*   cnt    = (int*)(total + 1);                    // 1    }
  int*   cntr   = cnt + 1;                              // K    }
  int*   ocnt   = cntr + K;                             // 1    }
  int zero_n = 256 + 1 + 1 + K + 1;
  size_t ews_off = (((size_t)(ocnt + 1 - (int*)w)) + 63) & ~(size_t)63;
  char* Ews = (char*)(w + ews_off);                     // K/64 tiles x 32KB = 4MB (fp16)

  k_pre<<<2048, 256, 0, stream>>>(embed, Ews, lslots, zero_n, ee, K, D);
  k_dist<<<T / 64, 256, 65536, stream>>>(x, Ews, ee, o_ind, idx, wl, cnt,
                                         cntr, rlist, olist, ocnt, T, K);
  k_fix1<<<1024, 256, 0, stream>>>(x, embed, ee, wl, cnt, pval, pidx);
  k_fix2<<<1024, 256, 0, stream>>>(wl, cnt, pval, pidx, o_ind, idx,
                                   cntr, rlist, olist, ocnt);
  k_mid<<<32, 256, 0, stream>>>(cs, cntr, o_ncs, total, x, embed, idx,
                                olist, ocnt, o_q, lslots, K);
  k_ema2<<<(K + 3) / 4, 256, 0, stream>>>(x, ea, embed, cntr, rlist, olist, ocnt,
                                          idx, o_ncs, total, o_ne, o_nea, o_q,
                                          lslots, K, D);
  k_loss<<<1, 256, 0, stream>>>(lslots, o_ls, COMMITF / ((float)T * (float)D));
}

// Round 22
// 420.700 us; speedup vs baseline: 2.4753x; 2.4753x over previous
//
#include <hip/hip_runtime.h>

#define DECAYF 0.8f
#define OMDF   0.2f
#define EPSF   1e-5f
#define COMMITF 1.0f
#define MARGINF 0.024f
#define FIXCAP  8192
#define MAXR    64

typedef _Float16 h8v __attribute__((ext_vector_type(8)));
typedef float f4v __attribute__((ext_vector_type(4)));

__device__ inline void gload_lds16(const void* g, void* l) {
  __builtin_amdgcn_global_load_lds(
      (const __attribute__((address_space(1))) unsigned int*)g,
      (__attribute__((address_space(3))) unsigned int*)l, 16, 0, 0);
}

// ---------------- fused: zero accumulators + embed->fp16 conv + 0.5||e||^2 ----------------
// Tile tt (64 codes): 32KB at Ews + tt*32768. value(c,d) at byte c*512 + ((d*2) ^ ((c&7)<<4)).
__global__ __launch_bounds__(256) void k_pre(
    const float* __restrict__ embed, char* __restrict__ Ews,
    float* __restrict__ zero_p, int zero_n, float* __restrict__ ee, int K, int D)
{
  const int tid = threadIdx.x;
  const int gid0 = blockIdx.x * 256 + tid;
  const int gstride = gridDim.x * 256;

  for (int i = gid0; i < zero_n; i += gstride) zero_p[i] = 0.0f;

  for (int gid = gid0; gid < K * (D / 8); gid += gstride) {
    int k = gid >> 5;
    int d0 = (gid & 31) * 8;
    const float* ep = embed + (size_t)k * D + d0;
    float4 v0 = *(const float4*)(ep);
    float4 v1 = *(const float4*)(ep + 4);
    float f[8] = {v0.x, v0.y, v0.z, v0.w, v1.x, v1.y, v1.z, v1.w};
    h8v h;
    float ss = 0.f;
#pragma unroll
    for (int e = 0; e < 8; ++e) {
      h[e] = (_Float16)f[e];
      ss = fmaf(f[e], f[e], ss);
    }
    int tt = k >> 6;
    int c = k & 63;
    int byteoff = c * 512 + ((d0 * 2) ^ ((c & 7) << 4));
    *(h8v*)(Ews + (size_t)tt * 32768 + byteoff) = h;
#pragma unroll
    for (int off = 1; off < 32; off <<= 1) ss += __shfl_xor(ss, off);
    if ((gid & 31) == 0) ee[k] = 0.5f * ss;
  }
}

// top-2 update with first-index tie-break (strict >)
__device__ __forceinline__ void upd2(float s, int code, float& b1, float& b2, int& bi) {
  if (s > b1) { b2 = b1; b1 = s; bi = code; }
  else if (s > b2) { b2 = s; }
}

// One tile body (barrier at end): MFMA tile TT into CUR; interleave top-2 of
// tile TT-1 (PRV). fp16 1-pass; 2-deep B-fragment register pipeline.
__device__ __forceinline__ void k_body(
    int TT, int NT, char* lds, const char* Ews, const float* ee,
    int w, int lane, int ch, int l15, int rowbyte0,
    const int (&dbyte)[8],
    const h8v (&xh)[2][8],
    f4v (&CUR)[2][2], f4v (&PRV)[2][2],
    float EEP0, float EEP1, float& EEC0, float& EEC1,
    float (&best)[2][4], float (&bst2)[2][4], int (&bidx)[2][4])
{
  const int k0 = TT * 64;
  const char* cb = lds + (TT & 1) * 32768;
  if (TT + 1 < NT) {
    const char* src = Ews + (size_t)(TT + 1) * 32768 + w * 8192 + lane * 16;
    char* dst = lds + ((TT + 1) & 1) * 32768 + w * 8192;
#pragma unroll
    for (int q = 0; q < 8; ++q) gload_lds16(src + q * 1024, dst + q * 1024);
  }
  EEC0 = ee[k0 + ch * 32 + l15];
  EEC1 = ee[k0 + ch * 32 + l15 + 16];
  const int c0p = k0 - 64 + ch * 32 + l15;
  const int c1p = c0p + 16;
#pragma unroll
  for (int rf = 0; rf < 2; ++rf) {
    CUR[rf][0] = (f4v){0.f, 0.f, 0.f, 0.f};
    CUR[rf][1] = (f4v){0.f, 0.f, 0.f, 0.f};
  }
  h8v Bh0[2], Bh1[2];
  {
    const char* p = cb + rowbyte0 + dbyte[0];
    Bh0[0] = *(const h8v*)(p);
    Bh1[0] = *(const h8v*)(p + 8192);
  }
#pragma unroll
  for (int ks = 0; ks < 8; ++ks) {
    const int cs = ks & 1, ns = cs ^ 1;
    if (ks < 7) {
      const char* p = cb + rowbyte0 + dbyte[ks + 1];
      Bh0[ns] = *(const h8v*)(p);
      Bh1[ns] = *(const h8v*)(p + 8192);
    }
    __builtin_amdgcn_s_setprio(1);
    CUR[0][0] = __builtin_amdgcn_mfma_f32_16x16x32_f16(xh[0][ks], Bh0[cs], CUR[0][0], 0, 0, 0);
    CUR[0][1] = __builtin_amdgcn_mfma_f32_16x16x32_f16(xh[0][ks], Bh1[cs], CUR[0][1], 0, 0, 0);
    CUR[1][0] = __builtin_amdgcn_mfma_f32_16x16x32_f16(xh[1][ks], Bh0[cs], CUR[1][0], 0, 0, 0);
    CUR[1][1] = __builtin_amdgcn_mfma_f32_16x16x32_f16(xh[1][ks], Bh1[cs], CUR[1][1], 0, 0, 0);
    __builtin_amdgcn_s_setprio(0);
    {
      const int rf = ks >> 2, ii = ks & 3;
      upd2(PRV[rf][0][ii] - EEP0, c0p, best[rf][ii], bst2[rf][ii], bidx[rf][ii]);
      upd2(PRV[rf][1][ii] - EEP1, c1p, best[rf][ii], bst2[rf][ii], bidx[rf][ii]);
    }
  }
  __syncthreads();
}

// ---------------- fused MFMA dist + argmax (+ near-tie flagging + CSR stats) ----------------
__global__ __launch_bounds__(256, 2) void k_dist(
    const float* __restrict__ x, const char* __restrict__ Ews,
    const float* __restrict__ ee, float* __restrict__ ind_f,
    int* __restrict__ idx_out, int* __restrict__ wl, int* __restrict__ cnt,
    int* __restrict__ cntr, int* __restrict__ rlist,
    int* __restrict__ olist, int* __restrict__ ocnt,
    int T, int K)
{
  extern __shared__ char lds[];   // 2 x 32768
  const int tid = threadIdx.x;
  const int w = tid >> 6, lane = tid & 63;
  const int l15 = lane & 15, lk = lane >> 4;
  const int rgrp = w >> 1, ch = w & 1;
  const int row0 = blockIdx.x * 64 + rgrp * 32;
  const int NT = K / 64;          // 128 (even)

  // X fragments (fp16): 2 rowfrags x 8 ksteps
  h8v xh[2][8];
#pragma unroll
  for (int rf = 0; rf < 2; ++rf) {
    const float* xp = x + (size_t)(row0 + rf * 16 + l15) * 256 + lk * 8;
#pragma unroll
    for (int ks = 0; ks < 8; ++ks) {
      float4 v0 = *(const float4*)(xp + ks * 32);
      float4 v1 = *(const float4*)(xp + ks * 32 + 4);
      float f[8] = {v0.x, v0.y, v0.z, v0.w, v1.x, v1.y, v1.z, v1.w};
      h8v h;
#pragma unroll
      for (int e = 0; e < 8; ++e) h[e] = (_Float16)f[e];
      xh[rf][ks] = h;
    }
  }

  float best[2][4], bst2[2][4];
  int bidx[2][4];
#pragma unroll
  for (int rf = 0; rf < 2; ++rf)
#pragma unroll
    for (int i = 0; i < 4; ++i) { best[rf][i] = -3.0e38f; bst2[rf][i] = -3.0e38f; bidx[rf][i] = 0; }

  const int swz = (l15 & 7) << 4;
  const int rowbyte0 = (ch * 32 + l15) * 512;
  int dbyte[8];
#pragma unroll
  for (int ks = 0; ks < 8; ++ks) dbyte[ks] = (ks * 64 + lk * 16) ^ swz;

  // prologue: stage tile 0 (32KB; 8KB per wave)
  {
    const char* src = Ews + (size_t)w * 8192 + lane * 16;
    char* dst = lds + w * 8192;
#pragma unroll
    for (int q = 0; q < 8; ++q)
      gload_lds16(src + q * 1024, dst + q * 1024);
  }
  __syncthreads();

  f4v accA[2][2], accB[2][2];
#pragma unroll
  for (int rf = 0; rf < 2; ++rf) {
    accB[rf][0] = (f4v){-3.0e38f, -3.0e38f, -3.0e38f, -3.0e38f};
    accB[rf][1] = (f4v){-3.0e38f, -3.0e38f, -3.0e38f, -3.0e38f};
  }
  float eeX0 = 0.f, eeX1 = 0.f, eeY0 = 0.f, eeY1 = 0.f;

  for (int tt = 0; tt < NT; tt += 2) {
    k_body(tt,     NT, lds, Ews, ee, w, lane, ch, l15, rowbyte0, dbyte, xh,
           accA, accB, eeX0, eeX1, eeY0, eeY1, best, bst2, bidx);
    k_body(tt + 1, NT, lds, Ews, ee, w, lane, ch, l15, rowbyte0, dbyte, xh,
           accB, accA, eeY0, eeY1, eeX0, eeX1, best, bst2, bidx);
  }
  // epilogue: top-2 of last tile (NT-1), acc in accB, ee pair in eeX
  {
    const int c0 = (NT - 1) * 64 + ch * 32 + l15, c1 = c0 + 16;
#pragma unroll
    for (int rf = 0; rf < 2; ++rf)
#pragma unroll
      for (int ii = 0; ii < 4; ++ii) {
        upd2(accB[rf][0][ii] - eeX0, c0, best[rf][ii], bst2[rf][ii], bidx[rf][ii]);
        upd2(accB[rf][1][ii] - eeX1, c1, best[rf][ii], bst2[rf][ii], bidx[rf][ii]);
      }
  }

  // reduce top-2 across the 16 column-lanes of each lk-group
#pragma unroll
  for (int rf = 0; rf < 2; ++rf)
#pragma unroll
    for (int i = 0; i < 4; ++i) {
      float s = best[rf][i], s2 = bst2[rf][i];
      int mi = bidx[rf][i];
#pragma unroll
      for (int off = 1; off < 16; off <<= 1) {
        float os = __shfl_xor(s, off);
        float os2 = __shfl_xor(s2, off);
        int oi = __shfl_xor(mi, off);
        if (os > s || (os == s && oi < mi)) {
          s2 = fmaxf(s, os2);
          s = os; mi = oi;
        } else {
          s2 = fmaxf(s2, os);
        }
      }
      best[rf][i] = s; bst2[rf][i] = s2; bidx[rf][i] = mi;
    }

  // ---- cross-ch merge via LDS (tile buffers dead after final barrier) ----
  float* S  = (float*)lds;
  float* S2 = S + 128;
  int*   MI = (int*)(S2 + 128);
  if (l15 == 0) {
#pragma unroll
    for (int rf = 0; rf < 2; ++rf)
#pragma unroll
      for (int i = 0; i < 4; ++i) {
        int rl = rf * 16 + lk * 4 + i;
        int a = rgrp * 64 + ch * 32 + rl;
        S[a]  = best[rf][i];
        S2[a] = bst2[rf][i];
        MI[a] = bidx[rf][i];
      }
  }
  __syncthreads();
  if (ch == 0 && lane < 32) {
    int a0 = rgrp * 64 + lane;
    float sA = S[a0],      s2A = S2[a0];      int miA = MI[a0];
    float sB = S[a0 + 32], s2B = S2[a0 + 32]; int miB = MI[a0 + 32];
    float s, s2; int mi;
    if (sB > sA || (sB == sA && miB < miA)) { s = sB; mi = miB; s2 = fmaxf(sA, s2B); }
    else                                    { s = sA; mi = miA; s2 = fmaxf(s2A, sB); }
    int row = row0 + lane;
    idx_out[row] = mi;
    ind_f[row] = (float)mi;
    int flagged = 0;
    if (s - s2 < MARGINF) {
      int slot = atomicAdd(cnt, 1);
      if (slot < FIXCAP) { wl[slot] = row; flagged = 1; }
    }
    if (!flagged) {
      int slot2 = atomicAdd(&cntr[mi], 1);
      if (slot2 < MAXR) rlist[mi * MAXR + slot2] = row;
      else { int o = atomicAdd(ocnt, 1); olist[o] = row; }
    }
  }
}

// ---------------- exact fp32 rescore, slice-parallel ----------------
__global__ __launch_bounds__(256) void k_fix1(
    const float* __restrict__ x, const float* __restrict__ embed,
    const float* __restrict__ ee, const int* __restrict__ wl,
    const int* __restrict__ cnt, float* __restrict__ pval,
    int* __restrict__ pidx)
{
  __shared__ float Xs[8][256];
  const int b = blockIdx.x & 255;
  const int g = blockIdx.x >> 8;
  const int t = threadIdx.x;
  int n = *cnt; if (n > FIXCAP) n = FIXCAP;
  const int c = b * 32 + (t & 31);
  const float* er = embed + (size_t)c * 256;
  const float eec = ee[c];
  const int rl = t >> 5;

  for (int r0 = g * 8; r0 < n; r0 += 32) {
    __syncthreads();
    for (int i = t; i < 8 * 64; i += 256) {
      int rr = i >> 6, dq = i & 63;
      int wi = r0 + rr; if (wi >= n) wi = n - 1;
      int row = wl[wi];
      ((float4*)Xs[rr])[dq] = *(const float4*)(x + (size_t)row * 256 + dq * 4);
    }
    __syncthreads();
    const float* xr = Xs[rl];
    float s0 = 0.f, s1 = 0.f, s2a = 0.f, s3 = 0.f;
#pragma unroll
    for (int d = 0; d < 256; d += 16) {
      float4 e0 = *(const float4*)(er + d);
      float4 e1 = *(const float4*)(er + d + 4);
      float4 e2 = *(const float4*)(er + d + 8);
      float4 e3 = *(const float4*)(er + d + 12);
      s0 = fmaf(xr[d + 0], e0.x, s0);  s0 = fmaf(xr[d + 1], e0.y, s0);
      s0 = fmaf(xr[d + 2], e0.z, s0);  s0 = fmaf(xr[d + 3], e0.w, s0);
      s1 = fmaf(xr[d + 4], e1.x, s1);  s1 = fmaf(xr[d + 5], e1.y, s1);
      s1 = fmaf(xr[d + 6], e1.z, s1);  s1 = fmaf(xr[d + 7], e1.w, s1);
      s2a = fmaf(xr[d + 8], e2.x, s2a);  s2a = fmaf(xr[d + 9], e2.y, s2a);
      s2a = fmaf(xr[d + 10], e2.z, s2a); s2a = fmaf(xr[d + 11], e2.w, s2a);
      s3 = fmaf(xr[d + 12], e3.x, s3);  s3 = fmaf(xr[d + 13], e3.y, s3);
      s3 = fmaf(xr[d + 14], e3.z, s3);  s3 = fmaf(xr[d + 15], e3.w, s3);
    }
    float s = ((s0 + s1) + (s2a + s3)) - eec;
    int mi = c;
#pragma unroll
    for (int off = 1; off < 32; off <<= 1) {
      float os = __shfl_xor(s, off);
      int oi = __shfl_xor(mi, off);
      if (os > s || (os == s && oi < mi)) { s = os; mi = oi; }
    }
    int wi = r0 + rl;
    if ((t & 31) == 0 && wi < n) {
      pval[(size_t)wi * 256 + b] = s;
      pidx[(size_t)wi * 256 + b] = mi;
    }
  }
}

// k_fix2: per flagged row, reduce 256 slice partials, write final idx + CSR stats.
__global__ __launch_bounds__(256) void k_fix2(
    const int* __restrict__ wl, const int* __restrict__ cnt,
    const float* __restrict__ pval, const int* __restrict__ pidx,
    float* __restrict__ ind_f, int* __restrict__ idx_out,
    int* __restrict__ cntr, int* __restrict__ rlist,
    int* __restrict__ olist, int* __restrict__ ocnt)
{
  __shared__ float bv[256];
  __shared__ int bi[256];
  const int t = threadIdx.x;
  int n = *cnt; if (n > FIXCAP) n = FIXCAP;
  for (int it = blockIdx.x; it < n; it += gridDim.x) {
    __syncthreads();
    bv[t] = pval[(size_t)it * 256 + t];
    bi[t] = pidx[(size_t)it * 256 + t];
    __syncthreads();
    for (int sh = 128; sh > 0; sh >>= 1) {
      if (t < sh) {
        if (bv[t + sh] > bv[t] || (bv[t + sh] == bv[t] && bi[t + sh] < bi[t])) {
          bv[t] = bv[t + sh]; bi[t] = bi[t + sh];
        }
      }
      __syncthreads();
    }
    if (t == 0) {
      int row = wl[it];
      int kf = bi[0];
      idx_out[row] = kf;
      ind_f[row] = (float)kf;
      int slot = atomicAdd(&cntr[kf], 1);
      if (slot < MAXR) rlist[kf * MAXR + slot] = row;
      else { int o = atomicAdd(ocnt, 1); olist[o] = row; }
    }
  }
}

// ---------------- k_mid: ncs+total + overflow drain (quant/loss/ovfsum for olist rows) ----
__global__ __launch_bounds__(256) void k_mid(
    const float* __restrict__ cs, const int* __restrict__ cntr,
    float* __restrict__ ncs, float* __restrict__ total_acc,
    const float* __restrict__ x, const float* __restrict__ embed,
    const int* __restrict__ idx, const int* __restrict__ olist,
    const int* __restrict__ ocnt, float* __restrict__ ovfsum,
    float* __restrict__ quant, float* __restrict__ lslots, int K)
{
  const int tid = threadIdx.x;
  const int wave = tid >> 6, lane = tid & 63;
  int k = blockIdx.x * 256 + tid;
  float v = cs[k] * DECAYF + OMDF * (float)cntr[k];
  ncs[k] = v;
  for (int off = 32; off > 0; off >>= 1) v += __shfl_down(v, off);
  __shared__ float s4[4];
  if ((tid & 63) == 0) s4[tid >> 6] = v;
  __syncthreads();
  if (tid == 0) atomicAdd(total_acc, s4[0] + s4[1] + s4[2] + s4[3]);
  // overflow rows (normally few): ovfsum + quant + loss
  int n = *ocnt;
  for (int i = blockIdx.x * 4 + wave; i < n; i += 128) {
    int row = olist[i];
    int kk = idx[row];
    int d0 = lane * 4;
    float4 xv = *(const float4*)(x + (size_t)row * 256 + d0);
    float4 ev = *(const float4*)(embed + (size_t)kk * 256 + d0);
    atomicAdd(&ovfsum[(size_t)kk * 256 + d0 + 0], xv.x);
    atomicAdd(&ovfsum[(size_t)kk * 256 + d0 + 1], xv.y);
    atomicAdd(&ovfsum[(size_t)kk * 256 + d0 + 2], xv.z);
    atomicAdd(&ovfsum[(size_t)kk * 256 + d0 + 3], xv.w);
    *(float4*)(quant + (size_t)row * 256 + d0) = ev;
    float dx = ev.x - xv.x, dy = ev.y - xv.y, dz = ev.z - xv.z, dw = ev.w - xv.w;
    float l = dx * dx + dy * dy + dz * dz + dw * dw;
    for (int off = 32; off > 0; off >>= 1) l += __shfl_down(l, off);
    if (lane == 0) atomicAdd(&lslots[row & 255], l);
  }
}

// ---------------- code-major segment-sum + EMA + smoothing + quant + loss ----------------
// One wave per code; embed row read ONCE per code serves all its rows' quant writes.
__global__ __launch_bounds__(256) void k_ema2(
    const float* __restrict__ x, const float* __restrict__ ea,
    const float* __restrict__ embed,
    const int* __restrict__ cntr, const int* __restrict__ rlist,
    const float* __restrict__ ovfsum, const float* __restrict__ ncs,
    const float* __restrict__ total_acc, float* __restrict__ ne,
    float* __restrict__ nea, float* __restrict__ quant,
    float* __restrict__ lslots, int K, int D)
{
  int wave = threadIdx.x >> 6, lane = threadIdx.x & 63;
  int k = blockIdx.x * 4 + wave;
  if (k >= K) return;
  int c = cntr[k];
  int m = c < MAXR ? c : MAXR;
  int d0 = lane * 4;
  float4 ev = *(const float4*)(embed + (size_t)k * 256 + d0);
  float4 s = *(const float4*)(ovfsum + (size_t)k * 256 + d0);
  float lsum = 0.f;
  for (int i = 0; i < m; ++i) {
    int r = rlist[k * MAXR + i];
    float4 xv = *(const float4*)(x + (size_t)r * 256 + d0);
    s.x += xv.x; s.y += xv.y; s.z += xv.z; s.w += xv.w;
    *(float4*)(quant + (size_t)r * 256 + d0) = ev;
    float dx = ev.x - xv.x, dy = ev.y - xv.y, dz = ev.z - xv.z, dw = ev.w - xv.w;
    lsum += dx * dx + dy * dy + dz * dz + dw * dw;
  }
  float4 eav = *(const float4*)(ea + (size_t)k * 256 + d0);
  float total = *total_acc;
  float csk = ncs[k];
  float sm = (csk + EPSF) / (total + (float)K * EPSF) * total;
  float rs = 1.0f / sm;
  float v0 = eav.x * DECAYF + OMDF * s.x;
  float v1 = eav.y * DECAYF + OMDF * s.y;
  float v2 = eav.z * DECAYF + OMDF * s.z;
  float v3 = eav.w * DECAYF + OMDF * s.w;
  size_t o = (size_t)k * 256 + d0;
  nea[o + 0] = v0; nea[o + 1] = v1; nea[o + 2] = v2; nea[o + 3] = v3;  // odd base: scalar stores
  ne[o + 0] = v0 * rs; ne[o + 1] = v1 * rs; ne[o + 2] = v2 * rs; ne[o + 3] = v3 * rs;
  // commit-loss partial for this code's rows
  for (int off = 32; off > 0; off >>= 1) lsum += __shfl_down(lsum, off);
  if (lane == 0 && m > 0) atomicAdd(&lslots[k & 255], lsum);
}

// ---------------- finalize commit loss ----------------
__global__ void k_loss(const float* __restrict__ lslots, float* __restrict__ out_loss,
                       float scale)
{
  int tid = threadIdx.x;
  float v = lslots[tid];
  for (int off = 32; off > 0; off >>= 1) v += __shfl_down(v, off);
  __shared__ float s4[4];
  if ((tid & 63) == 0) s4[tid >> 6] = v;
  __syncthreads();
  if (tid == 0) out_loss[0] = (s4[0] + s4[1] + s4[2] + s4[3]) * scale;
}

extern "C" void kernel_launch(void* const* d_in, const int* in_sizes, int n_in,
                              void* d_out, int out_size, void* d_ws, size_t ws_size,
                              hipStream_t stream)
{
  const float* x     = (const float*)d_in[0];
  const float* embed = (const float*)d_in[1];
  const float* cs    = (const float*)d_in[2];
  const float* ea    = (const float*)d_in[3];
  const int K = in_sizes[2];            // 8192
  const int D = in_sizes[1] / K;        // 256
  const int T = in_sizes[0] / D;        // 32768

  float* out   = (float*)d_out;
  float* o_q   = out;                        // T*D
  float* o_ind = out + (size_t)T * D;        // T
  float* o_ls  = o_ind + T;                  // 1
  float* o_ne  = o_ls + 1;                   // K*D
  float* o_ncs = o_ne + (size_t)K * D;       // K
  float* o_nea = o_ncs + K;                  // K*D

  float* w      = (float*)d_ws;
  float* ee     = w;                                    // K
  int*   idx    = (int*)(w + K);                        // T
  int*   wl     = idx + T;                              // FIXCAP
  float* pval   = (float*)(wl + FIXCAP);                // FIXCAP*256
  int*   pidx   = (int*)(pval + (size_t)FIXCAP * 256);  // FIXCAP*256
  int*   rlist  = pidx + (size_t)FIXCAP * 256;          // K*MAXR
  int*   olist  = rlist + (size_t)K * MAXR;             // T
  float* ovfsum = (float*)(olist + T);                  // K*D  } zeroed region
  float* lslots = ovfsum + (size_t)K * D;               // 256  }
  float* total  = lslots + 256;                         // 1    }
  int*   cnt    = (int*)(total + 1);                    // 1    }
  int*   cntr   = cnt + 1;                              // K    }
  int*   ocnt   = cntr + K;                             // 1    }
  int zero_n = K * D + 256 + 1 + 1 + K + 1;
  size_t ews_off = (((size_t)(ocnt + 1 - (int*)w)) + 63) & ~(size_t)63;
  char* Ews = (char*)(w + ews_off);                     // K/64 tiles x 32KB = 4MB (fp16)

  k_pre<<<2048, 256, 0, stream>>>(embed, Ews, ovfsum, zero_n, ee, K, D);
  k_dist<<<T / 64, 256, 65536, stream>>>(x, Ews, ee, o_ind, idx, wl, cnt,
                                         cntr, rlist, olist, ocnt, T, K);
  k_fix1<<<1024, 256, 0, stream>>>(x, embed, ee, wl, cnt, pval, pidx);
  k_fix2<<<1024, 256, 0, stream>>>(wl, cnt, pval, pidx, o_ind, idx,
                                   cntr, rlist, olist, ocnt);
  k_mid<<<32, 256, 0, stream>>>(cs, cntr, o_ncs, total, x, embed, idx,
                                olist, ocnt, ovfsum, o_q, lslots, K);
  k_ema2<<<(K + 3) / 4, 256, 0, stream>>>(x, ea, embed, cntr, rlist, ovfsum,
                                          o_ncs, total, o_ne, o_nea, o_q, lslots, K, D);
  k_loss<<<1, 256, 0, stream>>>(lslots, o_ls, COMMITF / ((float)T * (float)D));
}